// Round 5
// baseline (232.761 us; speedup 1.0000x reference)
//
#include <hip/hip_runtime.h>
#include <stdint.h>

#define B_DIM 8
#define N_DIM 2048
#define F_DIM 128
#define LN_EPS 1e-5f

typedef __attribute__((ext_vector_type(8))) short short8;
typedef __attribute__((ext_vector_type(4))) float floatx4;

// full RNE fp32 -> bf16
__device__ __forceinline__ ushort f2bf(float f) {
    union { float f; uint32_t u; } c;
    c.f = f;
    uint32_t u = c.u;
    return (ushort)((u + 0x7FFFu + ((u >> 16) & 1u)) >> 16);
}

// fast round-half-up pack of two fp32 -> packed bf16x2
__device__ __forceinline__ uint32_t pk2bf(float a, float b) {
    union { float f; uint32_t u; } x, y;
    x.f = a; y.f = b;
    return ((x.u + 0x8000u) >> 16) | ((y.u + 0x8000u) & 0xFFFF0000u);
}

__device__ __forceinline__ short8 pack8(float4 lo, float4 hi) {
    union { uint32_t u[4]; short8 s; } r;
    r.u[0] = pk2bf(lo.x, lo.y);
    r.u[1] = pk2bf(lo.z, lo.w);
    r.u[2] = pk2bf(hi.x, hi.y);
    r.u[3] = pk2bf(hi.z, hi.w);
    return r.s;
}

__device__ __forceinline__ void load_lds16(const ushort* g, ushort* l) {
    __builtin_amdgcn_global_load_lds(
        (const __attribute__((address_space(1))) void*)g,
        (__attribute__((address_space(3))) void*)l,
        16, 0, 0);
}

// ---------------------------------------------------------------------------
// Kernel 1: X (B, K=2048, F=128) fp32 -> Xt (B, F=128, K=2048) bf16.
// ---------------------------------------------------------------------------
__global__ __launch_bounds__(256) void k_transpose(const float* __restrict__ X,
                                                   ushort* __restrict__ Xt) {
    __shared__ ushort tile[64 * 65];
    const int t = threadIdx.x;
    const int b = blockIdx.z;
    const int k0 = blockIdx.x * 64;
    const int f0 = blockIdx.y * 64;

#pragma unroll
    for (int p = 0; p < 2; ++p) {
        int idx = p * 256 + t;
        int kk = idx >> 3;
        int ff = (idx & 7) * 8;
        const float* src = X + (((size_t)b * N_DIM) + k0 + kk) * F_DIM + f0 + ff;
        float4 v0 = *(const float4*)(src);
        float4 v1 = *(const float4*)(src + 4);
        ushort* d = tile + kk * 65 + ff;
        d[0] = f2bf(v0.x); d[1] = f2bf(v0.y); d[2] = f2bf(v0.z); d[3] = f2bf(v0.w);
        d[4] = f2bf(v1.x); d[5] = f2bf(v1.y); d[6] = f2bf(v1.z); d[7] = f2bf(v1.w);
    }
    __syncthreads();

    union U { uint4 v; ushort s[8]; };
#pragma unroll
    for (int p = 0; p < 2; ++p) {
        int idx = p * 256 + t;
        int f2 = idx >> 3;
        int kk2 = (idx & 7) * 8;
        U u;
#pragma unroll
        for (int j = 0; j < 8; ++j) u.s[j] = tile[(kk2 + j) * 65 + f2];
        *(uint4*)(Xt + (((size_t)b * F_DIM) + f0 + f2) * N_DIM + k0 + kk2) = u.v;
    }
}

// ---------------------------------------------------------------------------
// Kernel 2 (fused): H = A@X (bf16 MFMA), P = H@W^T + b, LN(128), ReLU.
// BM=16, BN=128, BK=128.  256 thr = 4 waves; wave w owns cols w*32..+32.
// LDS: K-loop {As 4K + Bs 32K} UNION epilogue {Ht + Pt} = 36.9 KB
//   -> 4 blocks/CU resident (grid 1024), 16 waves/CU: staging drains of
//      independent blocks interleave (m114 wave-level overlap).
// A: coalesced fp32 loads + reg pack + swizzled ds_write_b128 (A read once).
// B: global_load_lds 16B from bf16 Xt (L2-hot per-XCD: batch = bid&7).
// ---------------------------------------------------------------------------
union SMem {
    struct { ushort As[16 * 128]; ushort Bs[128 * 128]; } k;   // 36.9 KB
    struct { ushort Ht[16 * 136]; float Pt[16][132]; } e;      // 12.7 KB
};

__global__ __launch_bounds__(256) void k_fused(const float* __restrict__ A,
                                               const ushort* __restrict__ Xt,
                                               const float* __restrict__ W,
                                               const float* __restrict__ bias,
                                               const float* __restrict__ gamma,
                                               const float* __restrict__ beta,
                                               float* __restrict__ out) {
    __shared__ __align__(16) SMem sm;
    ushort* As = sm.k.As;
    ushort* Bs = sm.k.Bs;

    const int t = threadIdx.x;
    const int lane = t & 63;
    const int w = t >> 6;            // wave 0..3
    const int q = lane >> 4;         // 0..3
    const int mr = lane & 15;        // 0..15

    const int bid = blockIdx.x;
    const int bb = bid & 7;          // batch -> XCD affinity (L2 keeps Xt slice)
    const int m0 = (bid >> 3) * 16;  // M-tile origin (128 tiles per batch)

    const float* Ab = A + ((size_t)bb * N_DIM + m0) * N_DIM;
    const ushort* Xb = Xt + (size_t)bb * F_DIM * N_DIM;

    // A staging: thread t -> row (t>>4) of 16, 8 fp32 at k=(t&15)*8 (coalesced)
    const int arow = t >> 4;
    const int akc = t & 15;
    const float* a_src = Ab + (size_t)arow * N_DIM + akc * 8;
    ushort* a_dst = As + (arow * 16 + (akc ^ (arow & 7))) * 8;

    // B staging: 8 glds chunks/thread; LDS slot c = p*256+t (wave-contig),
    // source chunk kc = (c&15) ^ (n&7), n = c>>4.
    const ushort* b_src[8];
    ushort* b_dst[8];
#pragma unroll
    for (int p = 0; p < 8; ++p) {
        int c = p * 256 + t;
        int n = c >> 4;
        int kc = (c & 15) ^ (n & 7);
        b_src[p] = Xb + (size_t)n * N_DIM + kc * 8;
        b_dst[p] = Bs + c * 8;
    }

    floatx4 acc[2];
    acc[0] = (floatx4){0.f, 0.f, 0.f, 0.f};
    acc[1] = (floatx4){0.f, 0.f, 0.f, 0.f};

    for (int k0 = 0; k0 < N_DIM; k0 += 128) {
        // ---- stage: A fp32 (HBM) + async B (L2-hot)
        float4 v0 = ((const float4*)(a_src + k0))[0];
        float4 v1 = ((const float4*)(a_src + k0))[1];
#pragma unroll
        for (int p = 0; p < 8; ++p) load_lds16(b_src[p] + k0, b_dst[p]);
        *(short8*)a_dst = pack8(v0, v1);
        __syncthreads();

        // ---- compute: 8 MFMA / wave
#pragma unroll
        for (int ks = 0; ks < 4; ++ks) {
            short8 af = *(const short8*)(As + (mr * 16 + ((ks * 4 + q) ^ (mr & 7))) * 8);
#pragma unroll
            for (int j = 0; j < 2; ++j) {
                int n = w * 32 + j * 16 + mr;
                short8 bf = *(const short8*)(Bs + (n * 16 + ((ks * 4 + q) ^ (n & 7))) * 8);
                acc[j] = __builtin_amdgcn_mfma_f32_16x16x32_bf16(af, bf, acc[j], 0, 0, 0);
            }
        }
        __syncthreads();
    }

    // ---- epilogue buffers alias the K-loop LDS (dead after last barrier)
    ushort* Ht = sm.e.Ht;

    // scatter H tile (bf16). D layout: col=lane&15, row=q*4+reg [m89]
#pragma unroll
    for (int j = 0; j < 2; ++j) {
        int col = w * 32 + j * 16 + mr;
#pragma unroll
        for (int r = 0; r < 4; ++r)
            Ht[(q * 4 + r) * 136 + col] = f2bf(acc[j][r]);
    }
    __syncthreads();

    // ---- P[16x128] = Ht @ W^T  (W fp32 from global, L1/L2-hot)
    floatx4 p[2];
    p[0] = (floatx4){0.f, 0.f, 0.f, 0.f};
    p[1] = (floatx4){0.f, 0.f, 0.f, 0.f};

#pragma unroll
    for (int ks = 0; ks < 4; ++ks) {
        short8 ha = *(const short8*)(Ht + mr * 136 + ks * 32 + q * 8);
#pragma unroll
        for (int j = 0; j < 2; ++j) {
            const float* wp = W + (w * 32 + j * 16 + mr) * F_DIM + ks * 32 + q * 8;
            short8 wb = pack8(((const float4*)wp)[0], ((const float4*)wp)[1]);
            p[j] = __builtin_amdgcn_mfma_f32_16x16x32_bf16(ha, wb, p[j], 0, 0, 0);
        }
    }
    __syncthreads();  // Ht reads done before Pt writes overwrite the union

    // ---- bias add, scatter P (fp32) for row-major LN
#pragma unroll
    for (int j = 0; j < 2; ++j) {
        int col = w * 32 + j * 16 + mr;
        float bcol = bias[col];
#pragma unroll
        for (int r = 0; r < 4; ++r)
            sm.e.Pt[q * 4 + r][col] = p[j][r] + bcol;
    }
    __syncthreads();

    // ---- LayerNorm + ReLU: 16 lanes per row, 8 values each
    const int row = t >> 4;   // 0..15
    const int seg = t & 15;   // 0..15
    float v[8];
    float s = 0.f, s2 = 0.f;
#pragma unroll
    for (int u = 0; u < 8; ++u) {
        v[u] = sm.e.Pt[row][seg * 8 + u];
        s += v[u];
        s2 += v[u] * v[u];
    }
    s += __shfl_xor(s, 1);  s2 += __shfl_xor(s2, 1);
    s += __shfl_xor(s, 2);  s2 += __shfl_xor(s2, 2);
    s += __shfl_xor(s, 4);  s2 += __shfl_xor(s2, 4);
    s += __shfl_xor(s, 8);  s2 += __shfl_xor(s2, 8);
    float mu = s * (1.0f / 128.0f);
    float var = s2 * (1.0f / 128.0f) - mu * mu;
    float rs = rsqrtf(var + LN_EPS);

    float4 o[2];
    float* of = (float*)o;
#pragma unroll
    for (int u = 0; u < 8; ++u) {
        int d = seg * 8 + u;
        float y = (v[u] - mu) * rs * gamma[d] + beta[d];
        of[u] = fmaxf(y, 0.0f);
    }
    float4* dst = (float4*)(out + ((size_t)bb * N_DIM + m0 + row) * F_DIM + seg * 8);
    dst[0] = o[0];
    dst[1] = o[1];
}

// ---------------------------------------------------------------------------
extern "C" void kernel_launch(void* const* d_in, const int* in_sizes, int n_in,
                              void* d_out, int out_size, void* d_ws, size_t ws_size,
                              hipStream_t stream) {
    const float* A     = (const float*)d_in[0];
    const float* X     = (const float*)d_in[1];
    const float* W     = (const float*)d_in[2];
    const float* bias  = (const float*)d_in[3];
    const float* gamma = (const float*)d_in[4];
    const float* beta  = (const float*)d_in[5];
    float* out = (float*)d_out;

    ushort* Xt = (ushort*)d_ws;  // 4 MB bf16

    k_transpose<<<dim3(32, 2, 8), 256, 0, stream>>>(X, Xt);
    k_fused<<<dim3(1024), 256, 0, stream>>>(A, Xt, W, bias, gamma, beta, out);
}

// Round 6
// 218.914 us; speedup vs baseline: 1.0633x; 1.0633x over previous
//
#include <hip/hip_runtime.h>
#include <stdint.h>

#define B_DIM 8
#define N_DIM 2048
#define F_DIM 128
#define LN_EPS 1e-5f
#define NROWS (B_DIM * N_DIM)          // 16384 flat rows
#define HP_STRIDE ((size_t)NROWS * F_DIM)  // one partial buffer = 2M floats

typedef __attribute__((ext_vector_type(8))) short short8;
typedef __attribute__((ext_vector_type(4))) float floatx4;

// full RNE fp32 -> bf16
__device__ __forceinline__ ushort f2bf(float f) {
    union { float f; uint32_t u; } c;
    c.f = f;
    uint32_t u = c.u;
    return (ushort)((u + 0x7FFFu + ((u >> 16) & 1u)) >> 16);
}

// fast round-half-up pack of two fp32 -> packed bf16x2
__device__ __forceinline__ uint32_t pk2bf(float a, float b) {
    union { float f; uint32_t u; } x, y;
    x.f = a; y.f = b;
    return ((x.u + 0x8000u) >> 16) | ((y.u + 0x8000u) & 0xFFFF0000u);
}

__device__ __forceinline__ short8 pack8(float4 lo, float4 hi) {
    union { uint32_t u[4]; short8 s; } r;
    r.u[0] = pk2bf(lo.x, lo.y);
    r.u[1] = pk2bf(lo.z, lo.w);
    r.u[2] = pk2bf(hi.x, hi.y);
    r.u[3] = pk2bf(hi.z, hi.w);
    return r.s;
}

__device__ __forceinline__ void load_lds16(const ushort* g, ushort* l) {
    __builtin_amdgcn_global_load_lds(
        (const __attribute__((address_space(1))) void*)g,
        (__attribute__((address_space(3))) void*)l,
        16, 0, 0);
}

// ---------------------------------------------------------------------------
// Kernel 1: X (B, K=2048, F=128) fp32 -> Xt (B, F=128, K=2048) bf16.
// ---------------------------------------------------------------------------
__global__ __launch_bounds__(256) void k_transpose(const float* __restrict__ X,
                                                   ushort* __restrict__ Xt) {
    __shared__ ushort tile[64 * 65];
    const int t = threadIdx.x;
    const int b = blockIdx.z;
    const int k0 = blockIdx.x * 64;
    const int f0 = blockIdx.y * 64;

#pragma unroll
    for (int p = 0; p < 2; ++p) {
        int idx = p * 256 + t;
        int kk = idx >> 3;
        int ff = (idx & 7) * 8;
        const float* src = X + (((size_t)b * N_DIM) + k0 + kk) * F_DIM + f0 + ff;
        float4 v0 = *(const float4*)(src);
        float4 v1 = *(const float4*)(src + 4);
        ushort* d = tile + kk * 65 + ff;
        d[0] = f2bf(v0.x); d[1] = f2bf(v0.y); d[2] = f2bf(v0.z); d[3] = f2bf(v0.w);
        d[4] = f2bf(v1.x); d[5] = f2bf(v1.y); d[6] = f2bf(v1.z); d[7] = f2bf(v1.w);
    }
    __syncthreads();

    union U { uint4 v; ushort s[8]; };
#pragma unroll
    for (int p = 0; p < 2; ++p) {
        int idx = p * 256 + t;
        int f2 = idx >> 3;
        int kk2 = (idx & 7) * 8;
        U u;
#pragma unroll
        for (int j = 0; j < 8; ++j) u.s[j] = tile[(kk2 + j) * 65 + f2];
        *(uint4*)(Xt + (((size_t)b * F_DIM) + f0 + f2) * N_DIM + k0 + kk2) = u.v;
    }
}

// ---------------------------------------------------------------------------
// Kernel 2: split-K partial GEMM.  Hp[kh] += A[:, kh-half] @ X[kh-half, :].
// BM=32, BN=128, BK=128, 8 K-iters per block.  256 thr = 4 waves.
// Grid 1024 = 4 blocks/CU (LDS exactly 40 KB): 4 independent staging streams
// per CU so the per-iter vmcnt(0) barrier drains interleave (m114 overlap).
// A: fp32 coalesced + 1-iter register prefetch (A latency merged into the
//    same drain as B) + pack + swizzled ds_write_b128.  A read once total.
// B: global_load_lds 16B from bf16 Xt (L2-hot per-XCD: batch = bid&7).
// Partials written fp32 (no bf16 round until after the cross-half sum).
// ---------------------------------------------------------------------------
__global__ __launch_bounds__(256) void k_gemm_splitk(const float* __restrict__ A,
                                                     const ushort* __restrict__ Xt,
                                                     float* __restrict__ Hp) {
    __shared__ __align__(16) ushort As[32 * 128];   //  8 KB
    __shared__ __align__(16) ushort Bs[128 * 128];  // 32 KB

    const int t = threadIdx.x;
    const int lane = t & 63;
    const int w = t >> 6;            // wave 0..3
    const int q = lane >> 4;         // 0..3
    const int mr = lane & 15;        // 0..15

    const int bid = blockIdx.x;
    const int bb = bid & 7;          // batch -> XCD affinity
    const int idx = bid >> 3;        // 0..127
    const int kh = idx & 1;          // K-half
    const int m0 = (idx >> 1) * 32;  // M-tile origin
    const int kst = kh * 1024;       // K start

    const float* Ab = A + ((size_t)bb * N_DIM + m0) * N_DIM;
    const ushort* Xb = Xt + (size_t)bb * F_DIM * N_DIM;

    // A staging: thread t -> row (t>>3), 16 fp32 at k=(t&7)*16 (coalesced)
    const int arow = t >> 3;
    const float* a_src = Ab + (size_t)arow * N_DIM + (t & 7) * 16 + kst;
    ushort* a_dst0 = As + arow * 128 + ((((t & 7) * 2) ^ (arow & 7)) * 8);
    ushort* a_dst1 = As + arow * 128 + ((((t & 7) * 2 + 1) ^ (arow & 7)) * 8);

    // B staging: 8 glds chunks/thread; LDS slot c = p*256+t (wave-contig)
    const ushort* b_src[8];
    ushort* b_dst[8];
#pragma unroll
    for (int p = 0; p < 8; ++p) {
        int c = p * 256 + t;
        int n = c >> 4;
        int kc = (c & 15) ^ (n & 7);
        b_src[p] = Xb + (size_t)n * N_DIM + kc * 8 + kst;
        b_dst[p] = Bs + c * 8;
    }

    floatx4 acc[2][2];
#pragma unroll
    for (int i = 0; i < 2; ++i)
#pragma unroll
        for (int j = 0; j < 2; ++j) acc[i][j] = (floatx4){0.f, 0.f, 0.f, 0.f};

    // prime A regs for iter 0
    float4 c0 = ((const float4*)a_src)[0];
    float4 c1 = ((const float4*)a_src)[1];
    float4 c2 = ((const float4*)a_src)[2];
    float4 c3 = ((const float4*)a_src)[3];

    for (int it = 0; it < 8; ++it) {
        const int k0 = it * 128;
        // next-iter A loads first (deepest latency; merged into this drain).
        // Last iter: reload current (harmless, avoids UB / divergent branch).
        const float* pa = a_src + (it < 7 ? k0 + 128 : k0);
        float4 n0 = ((const float4*)pa)[0];
        float4 n1 = ((const float4*)pa)[1];
        float4 n2 = ((const float4*)pa)[2];
        float4 n3 = ((const float4*)pa)[3];
        // async B staging (L2-hot)
#pragma unroll
        for (int p = 0; p < 8; ++p) load_lds16(b_src[p] + k0, b_dst[p]);
        // pack + write current A
        *(short8*)a_dst0 = pack8(c0, c1);
        *(short8*)a_dst1 = pack8(c2, c3);
        __syncthreads();

#pragma unroll
        for (int ks = 0; ks < 4; ++ks) {
            short8 af[2], bf[2];
#pragma unroll
            for (int i = 0; i < 2; ++i) {
                int m = mr + i * 16;
                af[i] = *(const short8*)(As + m * 128 + (((ks * 4 + q) ^ (m & 7)) * 8));
            }
#pragma unroll
            for (int j = 0; j < 2; ++j) {
                int n = w * 32 + j * 16 + mr;
                bf[j] = *(const short8*)(Bs + n * 128 + (((ks * 4 + q) ^ (n & 7)) * 8));
            }
#pragma unroll
            for (int i = 0; i < 2; ++i)
#pragma unroll
                for (int j = 0; j < 2; ++j)
                    acc[i][j] = __builtin_amdgcn_mfma_f32_16x16x32_bf16(
                        af[i], bf[j], acc[i][j], 0, 0, 0);
        }
        __syncthreads();
        c0 = n0; c1 = n1; c2 = n2; c3 = n3;
    }

    // fp32 partial store. D layout: col=lane&15, row=q*4+reg [m89]
    float* Hb = Hp + (size_t)kh * HP_STRIDE + ((size_t)bb * N_DIM + m0) * F_DIM;
#pragma unroll
    for (int i = 0; i < 2; ++i)
#pragma unroll
        for (int j = 0; j < 2; ++j) {
            int col = w * 32 + j * 16 + mr;
#pragma unroll
            for (int r = 0; r < 4; ++r)
                Hb[(size_t)(i * 16 + q * 4 + r) * F_DIM + col] = acc[i][j][r];
        }
}

// ---------------------------------------------------------------------------
// Kernel 3: per 32 flat rows: H = Hp0+Hp1 (fp32->bf16), P = H@W^T + b,
// LayerNorm over 128, ReLU, fp32 out.  (Round-2 verified structure.)
// ---------------------------------------------------------------------------
__global__ __launch_bounds__(256) void k_linear_ln(const float* __restrict__ Hp,
                                                   const float* __restrict__ W,
                                                   const float* __restrict__ bias,
                                                   const float* __restrict__ gamma,
                                                   const float* __restrict__ beta,
                                                   float* __restrict__ out) {
    __shared__ __align__(16) ushort Ws[128 * 136];  // 34 KB
    __shared__ __align__(16) ushort Hs[32 * 136];   // 8.5 KB
    __shared__ __align__(16) float Pt[32][132];     // 16.5 KB

    const int t = threadIdx.x;
    const int lane = t & 63;
    const int w = t >> 6;
    const int q = lane >> 4;
    const int mr = lane & 15;
    const size_t r0 = (size_t)blockIdx.x * 32;   // flat row origin

    // stage W (fp32 -> bf16)
#pragma unroll
    for (int p = 0; p < 8; ++p) {
        int c = p * 256 + t;
        int d = c >> 4;
        int ff = (c & 15) * 8;
        const float* src = W + d * 128 + ff;
        *(short8*)(Ws + d * 136 + ff) =
            pack8(((const float4*)src)[0], ((const float4*)src)[1]);
    }
    // stage H = Hp0 + Hp1 (fp32 sum -> bf16)
#pragma unroll
    for (int p = 0; p < 2; ++p) {
        int c = p * 256 + t;
        int m = c >> 4;
        int ff = (c & 15) * 8;
        const float* h0 = Hp + (r0 + m) * F_DIM + ff;
        const float* h1 = h0 + HP_STRIDE;
        float4 a0 = ((const float4*)h0)[0];
        float4 a1 = ((const float4*)h0)[1];
        float4 b0 = ((const float4*)h1)[0];
        float4 b1 = ((const float4*)h1)[1];
        float4 s0 = {a0.x + b0.x, a0.y + b0.y, a0.z + b0.z, a0.w + b0.w};
        float4 s1 = {a1.x + b1.x, a1.y + b1.y, a1.z + b1.z, a1.w + b1.w};
        *(short8*)(Hs + m * 136 + ff) = pack8(s0, s1);
    }
    __syncthreads();

    floatx4 p[2][2];
#pragma unroll
    for (int i = 0; i < 2; ++i)
#pragma unroll
        for (int j = 0; j < 2; ++j) p[i][j] = (floatx4){0.f, 0.f, 0.f, 0.f};

#pragma unroll
    for (int ks = 0; ks < 4; ++ks) {
        short8 ha0 = *(const short8*)(Hs + mr * 136 + ks * 32 + q * 8);
        short8 ha1 = *(const short8*)(Hs + (mr + 16) * 136 + ks * 32 + q * 8);
#pragma unroll
        for (int j = 0; j < 2; ++j) {
            short8 wb = *(const short8*)(Ws + (w * 32 + j * 16 + mr) * 136 + ks * 32 + q * 8);
            p[0][j] = __builtin_amdgcn_mfma_f32_16x16x32_bf16(ha0, wb, p[0][j], 0, 0, 0);
            p[1][j] = __builtin_amdgcn_mfma_f32_16x16x32_bf16(ha1, wb, p[1][j], 0, 0, 0);
        }
    }

    // bias add, scatter P (fp32) for row-major LN
#pragma unroll
    for (int j = 0; j < 2; ++j) {
        int col = w * 32 + j * 16 + mr;
        float bcol = bias[col];
#pragma unroll
        for (int r = 0; r < 4; ++r) {
            Pt[q * 4 + r][col] = p[0][j][r] + bcol;
            Pt[16 + q * 4 + r][col] = p[1][j][r] + bcol;
        }
    }
    __syncthreads();

    // LayerNorm + ReLU: 8 lanes per row, 16 values each
    const int row = t >> 3;
    const int seg = t & 7;
    float v[16];
    float s = 0.f, s2 = 0.f;
#pragma unroll
    for (int u = 0; u < 16; ++u) {
        v[u] = Pt[row][seg * 16 + u];
        s += v[u];
        s2 += v[u] * v[u];
    }
    s += __shfl_xor(s, 1);  s2 += __shfl_xor(s2, 1);
    s += __shfl_xor(s, 2);  s2 += __shfl_xor(s2, 2);
    s += __shfl_xor(s, 4);  s2 += __shfl_xor(s2, 4);
    float mu = s * (1.0f / 128.0f);
    float var = s2 * (1.0f / 128.0f) - mu * mu;
    float rs = rsqrtf(var + LN_EPS);

    float4 o[4];
    float* of = (float*)o;
#pragma unroll
    for (int u = 0; u < 16; ++u) {
        int d = seg * 16 + u;
        float y = (v[u] - mu) * rs * gamma[d] + beta[d];
        of[u] = fmaxf(y, 0.0f);
    }
    float4* dst = (float4*)(out + (r0 + row) * F_DIM + seg * 16);
    dst[0] = o[0]; dst[1] = o[1]; dst[2] = o[2]; dst[3] = o[3];
}

// ---------------------------------------------------------------------------
extern "C" void kernel_launch(void* const* d_in, const int* in_sizes, int n_in,
                              void* d_out, int out_size, void* d_ws, size_t ws_size,
                              hipStream_t stream) {
    const float* A     = (const float*)d_in[0];
    const float* X     = (const float*)d_in[1];
    const float* W     = (const float*)d_in[2];
    const float* bias  = (const float*)d_in[3];
    const float* gamma = (const float*)d_in[4];
    const float* beta  = (const float*)d_in[5];
    float* out = (float*)d_out;

    ushort* Xt = (ushort*)d_ws;                                   // 4 MB bf16
    float* Hp = (float*)((char*)d_ws + (size_t)B_DIM * F_DIM * N_DIM * 2); // 2x8 MB fp32

    k_transpose<<<dim3(32, 2, 8), 256, 0, stream>>>(X, Xt);
    k_gemm_splitk<<<dim3(1024), 256, 0, stream>>>(A, Xt, Hp);
    k_linear_ln<<<dim3(512), 256, 0, stream>>>(Hp, W, bias, gamma, beta, out);
}

// Round 7
// 215.651 us; speedup vs baseline: 1.0793x; 1.0151x over previous
//
#include <hip/hip_runtime.h>
#include <stdint.h>

#define B_DIM 8
#define N_DIM 2048
#define F_DIM 128
#define LN_EPS 1e-5f

typedef __attribute__((ext_vector_type(8))) short short8;
typedef __attribute__((ext_vector_type(4))) float floatx4;

// full RNE fp32 -> bf16
__device__ __forceinline__ ushort f2bf(float f) {
    union { float f; uint32_t u; } c;
    c.f = f;
    uint32_t u = c.u;
    return (ushort)((u + 0x7FFFu + ((u >> 16) & 1u)) >> 16);
}

// fast round-half-up pack of two fp32 -> packed bf16x2
__device__ __forceinline__ uint32_t pk2bf(float a, float b) {
    union { float f; uint32_t u; } x, y;
    x.f = a; y.f = b;
    return ((x.u + 0x8000u) >> 16) | ((y.u + 0x8000u) & 0xFFFF0000u);
}

__device__ __forceinline__ short8 pack8(float4 lo, float4 hi) {
    union { uint32_t u[4]; short8 s; } r;
    r.u[0] = pk2bf(lo.x, lo.y);
    r.u[1] = pk2bf(lo.z, lo.w);
    r.u[2] = pk2bf(hi.x, hi.y);
    r.u[3] = pk2bf(hi.z, hi.w);
    return r.s;
}

__device__ __forceinline__ void load_lds16(const ushort* g, ushort* l) {
    __builtin_amdgcn_global_load_lds(
        (const __attribute__((address_space(1))) void*)g,
        (__attribute__((address_space(3))) void*)l,
        16, 0, 0);
}

// ---------------------------------------------------------------------------
// Kernel 1: X (B, K=2048, F=128) fp32 -> Xt (B, F=128, K=2048) bf16.
// ---------------------------------------------------------------------------
__global__ __launch_bounds__(256) void k_transpose(const float* __restrict__ X,
                                                   ushort* __restrict__ Xt) {
    __shared__ ushort tile[64 * 65];
    const int t = threadIdx.x;
    const int b = blockIdx.z;
    const int k0 = blockIdx.x * 64;
    const int f0 = blockIdx.y * 64;

#pragma unroll
    for (int p = 0; p < 2; ++p) {
        int idx = p * 256 + t;
        int kk = idx >> 3;
        int ff = (idx & 7) * 8;
        const float* src = X + (((size_t)b * N_DIM) + k0 + kk) * F_DIM + f0 + ff;
        float4 v0 = *(const float4*)(src);
        float4 v1 = *(const float4*)(src + 4);
        ushort* d = tile + kk * 65 + ff;
        d[0] = f2bf(v0.x); d[1] = f2bf(v0.y); d[2] = f2bf(v0.z); d[3] = f2bf(v0.w);
        d[4] = f2bf(v1.x); d[5] = f2bf(v1.y); d[6] = f2bf(v1.z); d[7] = f2bf(v1.w);
    }
    __syncthreads();

    union U { uint4 v; ushort s[8]; };
#pragma unroll
    for (int p = 0; p < 2; ++p) {
        int idx = p * 256 + t;
        int f2 = idx >> 3;
        int kk2 = (idx & 7) * 8;
        U u;
#pragma unroll
        for (int j = 0; j < 8; ++j) u.s[j] = tile[(kk2 + j) * 65 + f2];
        *(uint4*)(Xt + (((size_t)b * F_DIM) + f0 + f2) * N_DIM + k0 + kk2) = u.v;
    }
}

// ---------------------------------------------------------------------------
// Kernel 2 (fused): H = A@X (bf16 MFMA), P = H@W^T + b, LN(128), ReLU.
// BM=64, BN=128, BK=128, full K. Grid 256 = exactly 1 block/CU.
// 512 thr = 8 waves in a 2(m)x4(n) grid; each wave: 2x2 16x16x32 frags.
// 128 MFMA per barrier (2x round 4); B redundancy halved vs BM=32.
// A(fp32): coalesced loads + reg-prefetch issued AFTER the glds so the
//   barrier's waitcnt only drains the glds (vmcnt(4)) and next-iter A
//   stays in flight across the barrier (register dest = not LDS-visible).
// B(bf16 Xt): global_load_lds 16B, L2-hot per-XCD (batch = bid&7).
// Epilogue fused: W-proj + bias + LN + ReLU; LDS unioned (51.2 KB).
// ---------------------------------------------------------------------------
union SMem {
    struct { ushort As[64 * 128]; ushort Bs[128 * 128]; } k;  // 48 KB
    struct { ushort Ht[64 * 136]; float Pt[64][132]; } e;     // 51.2 KB
};

__global__ __launch_bounds__(512, 2) void k_fused(const float* __restrict__ A,
                                                  const ushort* __restrict__ Xt,
                                                  const float* __restrict__ W,
                                                  const float* __restrict__ bias,
                                                  const float* __restrict__ gamma,
                                                  const float* __restrict__ beta,
                                                  float* __restrict__ out) {
    __shared__ __align__(16) SMem sm;
    ushort* As = sm.k.As;
    ushort* Bs = sm.k.Bs;

    const int t = threadIdx.x;
    const int lane = t & 63;
    const int w = t >> 6;            // wave 0..7
    const int wm = w & 1;            // wave m-index (rows wm*32..+32)
    const int wn = w >> 1;           // wave n-index (cols wn*32..+32)
    const int q = lane >> 4;         // 0..3
    const int mr = lane & 15;        // 0..15

    const int bid = blockIdx.x;
    const int bb = bid & 7;          // batch -> XCD affinity
    const int m0 = (bid >> 3) * 64;  // M-tile origin (32 tiles/batch)

    const float* Ab = A + ((size_t)bb * N_DIM + m0) * N_DIM;
    const ushort* Xb = Xt + (size_t)bb * F_DIM * N_DIM;

    // A staging: thread t -> row (t>>3) (0..63), 16 fp32 at k=(t&7)*16
    const int ar = t >> 3;
    const float* a_src = Ab + (size_t)ar * N_DIM + (t & 7) * 16;
    ushort* a_dst0 = As + ar * 128 + ((((t & 7) * 2) ^ (ar & 7)) * 8);
    ushort* a_dst1 = As + ar * 128 + ((((t & 7) * 2 + 1) ^ (ar & 7)) * 8);

    // B staging: 4 glds chunks/thread; LDS slot c = p*512+t (wave-contig)
    const ushort* b_src[4];
    ushort* b_dst[4];
#pragma unroll
    for (int p = 0; p < 4; ++p) {
        int c = p * 512 + t;
        int n = c >> 4;                     // 0..127
        int kc = (c & 15) ^ (n & 7);        // swizzled source chunk
        b_src[p] = Xb + (size_t)n * N_DIM + kc * 8;
        b_dst[p] = Bs + c * 8;
    }

    floatx4 acc[2][2];
#pragma unroll
    for (int i = 0; i < 2; ++i)
#pragma unroll
        for (int j = 0; j < 2; ++j) acc[i][j] = (floatx4){0.f, 0.f, 0.f, 0.f};

    // prime A regs for iter 0
    float4 c0 = ((const float4*)a_src)[0];
    float4 c1 = ((const float4*)a_src)[1];
    float4 c2 = ((const float4*)a_src)[2];
    float4 c3 = ((const float4*)a_src)[3];

    for (int it = 0; it < 16; ++it) {
        const int k0 = it * 128;
        // (1) async B staging first (establishes glds position in vmcnt FIFO)
#pragma unroll
        for (int p = 0; p < 4; ++p) load_lds16(b_src[p] + k0, b_dst[p]);
        // (2) next-iter A register loads AFTER the glds: barrier drain can
        //     stop at vmcnt(4), leaving these in flight (reg dest).
        const float* pa = a_src + (it < 15 ? k0 + 128 : k0);
        float4 n0 = ((const float4*)pa)[0];
        float4 n1 = ((const float4*)pa)[1];
        float4 n2 = ((const float4*)pa)[2];
        float4 n3 = ((const float4*)pa)[3];
        // (3) pack + write current A (uses regs loaded last iter)
        *(short8*)a_dst0 = pack8(c0, c1);
        *(short8*)a_dst1 = pack8(c2, c3);
        __syncthreads();

        // (4) compute: 16 MFMA / wave
#pragma unroll
        for (int ks = 0; ks < 4; ++ks) {
            short8 af[2], bf[2];
#pragma unroll
            for (int i = 0; i < 2; ++i) {
                int m = wm * 32 + i * 16 + mr;
                af[i] = *(const short8*)(As + m * 128 + (((ks * 4 + q) ^ (m & 7)) * 8));
            }
#pragma unroll
            for (int j = 0; j < 2; ++j) {
                int n = wn * 32 + j * 16 + mr;
                bf[j] = *(const short8*)(Bs + n * 128 + (((ks * 4 + q) ^ (n & 7)) * 8));
            }
#pragma unroll
            for (int i = 0; i < 2; ++i)
#pragma unroll
                for (int j = 0; j < 2; ++j)
                    acc[i][j] = __builtin_amdgcn_mfma_f32_16x16x32_bf16(
                        af[i], bf[j], acc[i][j], 0, 0, 0);
        }
        __syncthreads();
        c0 = n0; c1 = n1; c2 = n2; c3 = n3;
    }

    // ---- epilogue (LDS union; K-loop buffers dead) -------------------------
    ushort* Ht = sm.e.Ht;

    // scatter H (bf16). D layout: col=lane&15, row=q*4+reg [m89]
#pragma unroll
    for (int i = 0; i < 2; ++i)
#pragma unroll
        for (int j = 0; j < 2; ++j) {
            int col = wn * 32 + j * 16 + mr;
#pragma unroll
            for (int r = 0; r < 4; ++r)
                Ht[(wm * 32 + i * 16 + q * 4 + r) * 136 + col] = f2bf(acc[i][j][r]);
        }
    __syncthreads();

    // P[64x128] = Ht @ W^T  (W fp32 from global, L2-hot)
    floatx4 p[2][2];
#pragma unroll
    for (int i = 0; i < 2; ++i)
#pragma unroll
        for (int j = 0; j < 2; ++j) p[i][j] = (floatx4){0.f, 0.f, 0.f, 0.f};

#pragma unroll
    for (int ks = 0; ks < 4; ++ks) {
        short8 ha0 = *(const short8*)(Ht + (wm * 32 + mr) * 136 + ks * 32 + q * 8);
        short8 ha1 = *(const short8*)(Ht + (wm * 32 + 16 + mr) * 136 + ks * 32 + q * 8);
#pragma unroll
        for (int j = 0; j < 2; ++j) {
            const float* wp = W + (wn * 32 + j * 16 + mr) * F_DIM + ks * 32 + q * 8;
            short8 wb = pack8(((const float4*)wp)[0], ((const float4*)wp)[1]);
            p[0][j] = __builtin_amdgcn_mfma_f32_16x16x32_bf16(ha0, wb, p[0][j], 0, 0, 0);
            p[1][j] = __builtin_amdgcn_mfma_f32_16x16x32_bf16(ha1, wb, p[1][j], 0, 0, 0);
        }
    }

    // bias add, scatter P (fp32) for row-major LN  (Pt does not alias Ht)
#pragma unroll
    for (int j = 0; j < 2; ++j) {
        int col = wn * 32 + j * 16 + mr;
        float bcol = bias[col];
#pragma unroll
        for (int r = 0; r < 4; ++r) {
            sm.e.Pt[wm * 32 + q * 4 + r][col] = p[0][j][r] + bcol;
            sm.e.Pt[wm * 32 + 16 + q * 4 + r][col] = p[1][j][r] + bcol;
        }
    }
    __syncthreads();

    // LayerNorm + ReLU: 8 lanes per row, 16 values each (rows 0..63)
    const int row = t >> 3;
    const int seg = t & 7;
    float v[16];
    float s = 0.f, s2 = 0.f;
#pragma unroll
    for (int u = 0; u < 16; ++u) {
        v[u] = sm.e.Pt[row][seg * 16 + u];
        s += v[u];
        s2 += v[u] * v[u];
    }
    s += __shfl_xor(s, 1);  s2 += __shfl_xor(s2, 1);
    s += __shfl_xor(s, 2);  s2 += __shfl_xor(s2, 2);
    s += __shfl_xor(s, 4);  s2 += __shfl_xor(s2, 4);
    float mu = s * (1.0f / 128.0f);
    float var = s2 * (1.0f / 128.0f) - mu * mu;
    float rs = rsqrtf(var + LN_EPS);

    float4 o[4];
    float* of = (float*)o;
#pragma unroll
    for (int u = 0; u < 16; ++u) {
        int d = seg * 16 + u;
        float y = (v[u] - mu) * rs * gamma[d] + beta[d];
        of[u] = fmaxf(y, 0.0f);
    }
    float4* dst = (float4*)(out + ((size_t)bb * N_DIM + m0 + row) * F_DIM + seg * 16);
    dst[0] = o[0]; dst[1] = o[1]; dst[2] = o[2]; dst[3] = o[3];
}

// ---------------------------------------------------------------------------
extern "C" void kernel_launch(void* const* d_in, const int* in_sizes, int n_in,
                              void* d_out, int out_size, void* d_ws, size_t ws_size,
                              hipStream_t stream) {
    const float* A     = (const float*)d_in[0];
    const float* X     = (const float*)d_in[1];
    const float* W     = (const float*)d_in[2];
    const float* bias  = (const float*)d_in[3];
    const float* gamma = (const float*)d_in[4];
    const float* beta  = (const float*)d_in[5];
    float* out = (float*)d_out;

    ushort* Xt = (ushort*)d_ws;  // 4 MB bf16

    k_transpose<<<dim3(32, 2, 8), 256, 0, stream>>>(X, Xt);
    k_fused<<<dim3(256), 512, 0, stream>>>(A, Xt, W, bias, gamma, beta, out);
}